// Round 7
// baseline (507.748 us; speedup 1.0000x reference)
//
#include <hip/hip_runtime.h>

#define N_NODES 50000
#define E_EDGES 800000
#define F_IN 512
#define HID 128
#define N_LAYERS 4
#define C_OUT 40
#define SCAN_BLOCKS 196   // ceil(50000/256)
#define NS_IN 16          // F_IN/32 K-steps

typedef __attribute__((ext_vector_type(8))) short bf16x8;
typedef __attribute__((ext_vector_type(4))) float f32x4;

#define MFMA16(a, b, c) __builtin_amdgcn_mfma_f32_16x16x32_bf16(a, b, c, 0, 0, 0)

// split fp32 into bf16 hi (RNE) + bf16 lo (residual); a ~= hi + lo with ~2^-17 rel error
__device__ __forceinline__ void split2(float a, unsigned short& hi, unsigned short& lo) {
    unsigned u = __float_as_uint(a);
    unsigned r = u + 0x7FFFu + ((u >> 16) & 1u);
    hi = (unsigned short)(r >> 16);
    float hf = __uint_as_float(((unsigned)hi) << 16);
    lo = (unsigned short)(__float_as_uint(a - hf) >> 16);
}

// 8 floats -> bf16x8 hi/lo fragments
__device__ __forceinline__ void splitfrag(float4 a, float4 b, bf16x8& h8, bf16x8& l8) {
    unsigned short hh, ll;
    float v[8] = {a.x, a.y, a.z, a.w, b.x, b.y, b.z, b.w};
    #pragma unroll
    for (int i = 0; i < 8; i++) {
        split2(v[i], hh, ll);
        h8[i] = (short)hh;
        l8[i] = (short)ll;
    }
}

// async global->LDS 16B DMA
__device__ __forceinline__ void async16(void* lds, const void* g) {
    __builtin_amdgcn_global_load_lds(
        (const __attribute__((address_space(1))) unsigned*)g,
        (__attribute__((address_space(3))) unsigned*)lds, 16, 0, 0);
}

// ---------------- degree / norm ----------------
__global__ void indeg_count(const int* __restrict__ ei, int* __restrict__ indeg) {
    int e = blockIdx.x * 256 + threadIdx.x;
    if (e < E_EDGES) {
        unsigned d = (unsigned)ei[E_EDGES + e];
        if (d < N_NODES) atomicAdd(&indeg[d], 1);
    }
}

// ---------------- 3-phase parallel exclusive scan (+ dinv fused in p1) ----------------
__global__ void scan_p1(const int* __restrict__ indeg, int* __restrict__ bsum,
                        float* __restrict__ dinv) {
    __shared__ int red[4];
    int i = blockIdx.x * 256 + threadIdx.x;
    int v = (i < N_NODES) ? indeg[i] : 0;
    if (i < N_NODES) dinv[i] = rsqrtf(1.0f + (float)v);   // +1 self-loop
    int s = v;
    #pragma unroll
    for (int off = 32; off > 0; off >>= 1) s += __shfl_down(s, off, 64);
    if ((threadIdx.x & 63) == 0) red[threadIdx.x >> 6] = s;
    __syncthreads();
    if (threadIdx.x == 0) bsum[blockIdx.x] = red[0] + red[1] + red[2] + red[3];
}

__launch_bounds__(256)
__global__ void scan_p2(const int* __restrict__ bsum, int* __restrict__ boff,
                        int* __restrict__ rowptr) {
    __shared__ int s[256];
    int t = threadIdx.x;
    int v = (t < SCAN_BLOCKS) ? bsum[t] : 0;
    s[t] = v;
    __syncthreads();
    #pragma unroll
    for (int off = 1; off < 256; off <<= 1) {
        int a = s[t];
        int b = (t >= off) ? s[t - off] : 0;
        __syncthreads();
        s[t] = a + b;
        __syncthreads();
    }
    if (t < SCAN_BLOCKS) boff[t] = (t == 0) ? 0 : s[t - 1];
    if (t == 255) rowptr[N_NODES] = s[SCAN_BLOCKS - 1];
}

__launch_bounds__(256)
__global__ void scan_p3(const int* __restrict__ indeg, const int* __restrict__ boff,
                        int* __restrict__ rowptr, int* __restrict__ cursor) {
    __shared__ int s[256];
    int t = threadIdx.x;
    int i = blockIdx.x * 256 + t;
    int v = (i < N_NODES) ? indeg[i] : 0;
    s[t] = v;
    __syncthreads();
    #pragma unroll
    for (int off = 1; off < 256; off <<= 1) {
        int a = s[t];
        int b = (t >= off) ? s[t - off] : 0;
        __syncthreads();
        s[t] = a + b;
        __syncthreads();
    }
    if (i < N_NODES) {
        int excl = boff[blockIdx.x] + s[t] - v;
        rowptr[i] = excl;
        cursor[i] = excl;
    }
}

// ---------------- CSR fill: (src, dinv[src]) packed ----------------
__global__ void csr_fill(const int* __restrict__ ei, const float* __restrict__ dinv,
                         int* __restrict__ cursor, int2* __restrict__ csr) {
    int e = blockIdx.x * 256 + threadIdx.x;
    if (e < E_EDGES) {
        unsigned s = (unsigned)ei[e];
        unsigned d = (unsigned)ei[E_EDGES + e];
        if (s < N_NODES && d < N_NODES) {
            int pos = atomicAdd(&cursor[d], 1);
            csr[pos] = make_int2((int)s, __float_as_int(dinv[s]));
        }
    }
}

// ---------------- merged weight prep: fp32 W[K][N] -> hi/lo bf16 [N][K] ----------------
__global__ void wprep(const float* __restrict__ Wi, const float* __restrict__ Wl,
                      unsigned short* __restrict__ Wth, unsigned short* __restrict__ Wtl,
                      unsigned short* __restrict__ Wlth, unsigned short* __restrict__ Wltl) {
    int idx = blockIdx.x * 256 + threadIdx.x;
    unsigned short hi, lo;
    if (idx < F_IN * HID) {                       // 65536: input weights
        int k = idx >> 7, n = idx & 127;
        split2(Wi[idx], hi, lo);
        Wth[(size_t)n * F_IN + k] = hi;
        Wtl[(size_t)n * F_IN + k] = lo;
    } else if (idx < 2 * F_IN * HID) {            // 65536: layer weights (4x128x128)
        int j = idx - F_IN * HID;
        int l = j >> 14, rem = j & 16383;
        int k = rem >> 7, n = rem & 127;
        split2(Wl[j], hi, lo);
        Wlth[(size_t)l * HID * HID + n * HID + k] = hi;
        Wltl[(size_t)l * HID * HID + n * HID + k] = lo;
    }
}

// ---------------- input GEMM (MFMA split-bf16): x0 = relu(x @ W_in + b) ----------------
// BM=64, BN=128, BK=32, 16 steps. A direct from global (reg prefetch 1 step ahead);
// B double-buffered in LDS via global_load_lds (swizzled source), ONE barrier per step.
__launch_bounds__(256)
__global__ void gemm_in_mfma(const float* __restrict__ x,
                             const unsigned short* __restrict__ Bth,
                             const unsigned short* __restrict__ Btl,
                             const float* __restrict__ bi,
                             float* __restrict__ x0out) {
    __shared__ __align__(16) unsigned short Bh[2][128 * 32];   // 2 x 8 KB
    __shared__ __align__(16) unsigned short Bl[2][128 * 32];   // 2 x 8 KB
    const int t = threadIdx.x;
    const int lane = t & 63;
    const int wv = t >> 6;
    const int wr = wv >> 1, wc = wv & 1;
    const int row0 = blockIdx.x * 64;
    const int fr = lane & 15;
    const int fkg = lane >> 4;

    const int ar0 = row0 + wr * 32 + fr;        // mt=0 row
    const int ar1 = ar0 + 16;                   // mt=1 row
    const bool ok0 = ar0 < N_NODES, ok1 = ar1 < N_NODES;
    const float* xp0 = x + (size_t)ar0 * F_IN + fkg * 8;
    const float* xp1 = x + (size_t)ar1 * F_IN + fkg * 8;
    const float4 z4 = make_float4(0.f, 0.f, 0.f, 0.f);

    f32x4 acc[2][4] = {};

    // B stage: LDS granule g holds source k-granule (kg ^ s(n)); reader applies same XOR.
    // s(n) = (n + n/4) & 3 spreads the 16-bank row stride -> 2-way (free) on ds_read_b128.
    auto stageB = [&](int buf, int step) {
        int kbase = step * 32;
        #pragma unroll
        for (int i = 0; i < 2; i++) {
            int g = t + i * 256;                  // 0..511
            int n = g >> 2, kg = g & 3;
            int sw = (n + (n >> 2)) & 3;
            size_t src = (size_t)n * F_IN + kbase + ((kg ^ sw) * 8);
            async16(&Bh[buf][g * 8], &Bth[src]);
            async16(&Bl[buf][g * 8], &Btl[src]);
        }
    };

    // prologue: A regs for step 0, B buf0
    float4 xc0a = ok0 ? *(const float4*)(xp0 + 0) : z4;
    float4 xc0b = ok0 ? *(const float4*)(xp0 + 4) : z4;
    float4 xc1a = ok1 ? *(const float4*)(xp1 + 0) : z4;
    float4 xc1b = ok1 ? *(const float4*)(xp1 + 4) : z4;
    stageB(0, 0);
    __syncthreads();

    int cur = 0;
    for (int step = 0; step < NS_IN; step++) {
        float4 xn0a = z4, xn0b = z4, xn1a = z4, xn1b = z4;
        if (step + 1 < NS_IN) {
            const float* p0 = xp0 + (step + 1) * 32;
            const float* p1 = xp1 + (step + 1) * 32;
            if (ok0) { xn0a = *(const float4*)(p0 + 0); xn0b = *(const float4*)(p0 + 4); }
            if (ok1) { xn1a = *(const float4*)(p1 + 0); xn1b = *(const float4*)(p1 + 4); }
            stageB(cur ^ 1, step + 1);            // DMA issued early, hides under MFMA
        }

        bf16x8 ah0, al0, ah1, al1;
        splitfrag(xc0a, xc0b, ah0, al0);
        splitfrag(xc1a, xc1b, ah1, al1);

        #pragma unroll
        for (int nt = 0; nt < 4; nt++) {
            int n = wc * 64 + nt * 16 + fr;
            int sw = (n + (n >> 2)) & 3;
            int g = n * 4 + (fkg ^ sw);
            bf16x8 bh = *(bf16x8*)&Bh[cur][g * 8];
            bf16x8 bl = *(bf16x8*)&Bl[cur][g * 8];
            acc[0][nt] = MFMA16(al0, bh, acc[0][nt]);
            acc[0][nt] = MFMA16(ah0, bl, acc[0][nt]);
            acc[0][nt] = MFMA16(ah0, bh, acc[0][nt]);
            acc[1][nt] = MFMA16(al1, bh, acc[1][nt]);
            acc[1][nt] = MFMA16(ah1, bl, acc[1][nt]);
            acc[1][nt] = MFMA16(ah1, bh, acc[1][nt]);
        }
        __syncthreads();     // drains next-step DMA + guards buf reuse
        cur ^= 1;
        xc0a = xn0a; xc0b = xn0b; xc1a = xn1a; xc1b = xn1b;
    }

    const int dcol = lane & 15;
    const int dr0 = (lane >> 4) * 4;
    #pragma unroll
    for (int nt = 0; nt < 4; nt++) {
        int gcol = wc * 64 + nt * 16 + dcol;
        float b = bi[gcol];
        #pragma unroll
        for (int mt = 0; mt < 2; mt++) {
            #pragma unroll
            for (int j = 0; j < 4; j++) {
                int grow = row0 + wr * 32 + mt * 16 + dr0 + j;
                if (grow < N_NODES) {
                    x0out[(size_t)grow * HID + gcol] = fmaxf(acc[mt][nt][j] + b, 0.f);
                }
            }
        }
    }
}

// ---------------- aggregate (CSR gather, packed weights) + residual combine ----------------
// Half-wave per dst node; lane owns float4; 8 row-loads in flight.
__launch_bounds__(256)
__global__ void aggregate(const int* __restrict__ rowptr, const int2* __restrict__ csr,
                          const float* __restrict__ dinv,
                          const float* __restrict__ h, const float* __restrict__ x0,
                          float* __restrict__ comb) {
    const int hw = threadIdx.x >> 5;
    const int lane = threadIdx.x & 31;
    const int node = blockIdx.x * 8 + hw;
    if (node >= N_NODES) return;

    const float4* h4 = (const float4*)h;
    const float4* x4 = (const float4*)x0;
    const float dd = dinv[node];
    const int beg = rowptr[node];
    const int end = rowptr[node + 1];

    float4 a0 = make_float4(0.f, 0.f, 0.f, 0.f);
    float4 a1 = make_float4(0.f, 0.f, 0.f, 0.f);
    float4 a2 = make_float4(0.f, 0.f, 0.f, 0.f);
    float4 a3 = make_float4(0.f, 0.f, 0.f, 0.f);
    int e = beg;
    for (; e + 8 <= end; e += 8) {
        int2 c0 = csr[e + 0], c1 = csr[e + 1], c2 = csr[e + 2], c3 = csr[e + 3];
        int2 c4 = csr[e + 4], c5 = csr[e + 5], c6 = csr[e + 6], c7 = csr[e + 7];
        float4 v0 = h4[(size_t)c0.x * 32 + lane];
        float4 v1 = h4[(size_t)c1.x * 32 + lane];
        float4 v2 = h4[(size_t)c2.x * 32 + lane];
        float4 v3 = h4[(size_t)c3.x * 32 + lane];
        float4 v4 = h4[(size_t)c4.x * 32 + lane];
        float4 v5 = h4[(size_t)c5.x * 32 + lane];
        float4 v6 = h4[(size_t)c6.x * 32 + lane];
        float4 v7 = h4[(size_t)c7.x * 32 + lane];
        float w0 = __int_as_float(c0.y), w1 = __int_as_float(c1.y);
        float w2 = __int_as_float(c2.y), w3 = __int_as_float(c3.y);
        float w4 = __int_as_float(c4.y), w5 = __int_as_float(c5.y);
        float w6 = __int_as_float(c6.y), w7 = __int_as_float(c7.y);
        a0.x = fmaf(w0, v0.x, a0.x); a0.y = fmaf(w0, v0.y, a0.y);
        a0.z = fmaf(w0, v0.z, a0.z); a0.w = fmaf(w0, v0.w, a0.w);
        a1.x = fmaf(w1, v1.x, a1.x); a1.y = fmaf(w1, v1.y, a1.y);
        a1.z = fmaf(w1, v1.z, a1.z); a1.w = fmaf(w1, v1.w, a1.w);
        a2.x = fmaf(w2, v2.x, a2.x); a2.y = fmaf(w2, v2.y, a2.y);
        a2.z = fmaf(w2, v2.z, a2.z); a2.w = fmaf(w2, v2.w, a2.w);
        a3.x = fmaf(w3, v3.x, a3.x); a3.y = fmaf(w3, v3.y, a3.y);
        a3.z = fmaf(w3, v3.z, a3.z); a3.w = fmaf(w3, v3.w, a3.w);
        a0.x = fmaf(w4, v4.x, a0.x); a0.y = fmaf(w4, v4.y, a0.y);
        a0.z = fmaf(w4, v4.z, a0.z); a0.w = fmaf(w4, v4.w, a0.w);
        a1.x = fmaf(w5, v5.x, a1.x); a1.y = fmaf(w5, v5.y, a1.y);
        a1.z = fmaf(w5, v5.z, a1.z); a1.w = fmaf(w5, v5.w, a1.w);
        a2.x = fmaf(w6, v6.x, a2.x); a2.y = fmaf(w6, v6.y, a2.y);
        a2.z = fmaf(w6, v6.z, a2.z); a2.w = fmaf(w6, v6.w, a2.w);
        a3.x = fmaf(w7, v7.x, a3.x); a3.y = fmaf(w7, v7.y, a3.y);
        a3.z = fmaf(w7, v7.z, a3.z); a3.w = fmaf(w7, v7.w, a3.w);
    }
    for (; e < end; e++) {
        int2 c = csr[e];
        float w = __int_as_float(c.y);
        float4 v = h4[(size_t)c.x * 32 + lane];
        a0.x = fmaf(w, v.x, a0.x); a0.y = fmaf(w, v.y, a0.y);
        a0.z = fmaf(w, v.z, a0.z); a0.w = fmaf(w, v.w, a0.w);
    }
    float4 sum;
    sum.x = (a0.x + a1.x) + (a2.x + a3.x);
    sum.y = (a0.y + a1.y) + (a2.y + a3.y);
    sum.z = (a0.z + a1.z) + (a2.z + a3.z);
    sum.w = (a0.w + a1.w) + (a2.w + a3.w);

    float4 hv = h4[(size_t)node * 32 + lane];
    float4 xv = x4[(size_t)node * 32 + lane];
    const float a = 0.8f * dd;
    float4 o;
    o.x = a * fmaf(dd, hv.x, sum.x) + 0.1f * hv.x + 0.1f * xv.x;
    o.y = a * fmaf(dd, hv.y, sum.y) + 0.1f * hv.y + 0.1f * xv.y;
    o.z = a * fmaf(dd, hv.z, sum.z) + 0.1f * hv.z + 0.1f * xv.z;
    o.w = a * fmaf(dd, hv.w, sum.w) + 0.1f * hv.w + 0.1f * xv.w;
    ((float4*)comb)[(size_t)node * 32 + lane] = o;
}

// ---------------- layer GEMM (MFMA split-bf16, in place): comb <- SReLU(comb @ W) ----------------
__launch_bounds__(256)
__global__ void gemm_layer_mfma(const unsigned short* __restrict__ Bth,
                                const unsigned short* __restrict__ Btl,
                                const float* __restrict__ sb,
                                float* __restrict__ comb) {
    __shared__ __align__(16) unsigned short Ah[64 * 128];
    __shared__ __align__(16) unsigned short Al[64 * 128];
    __shared__ __align__(16) unsigned short Bh[128 * 64];
    __shared__ __align__(16) unsigned short Bl[128 * 64];
    const int t = threadIdx.x;
    const int lane = t & 63;
    const int wv = t >> 6;
    const int wr = wv >> 1, wc = wv & 1;
    const int row0 = blockIdx.x * 64;
    const int fr = lane & 15;
    const int fkg = lane >> 4;

    f32x4 acc[2][4] = {};

    auto stageB = [&](int khalf) {
        #pragma unroll
        for (int i = 0; i < 4; i++) {
            int g = t + i * 256;
            int n = g >> 3, j = g & 7;
            int jp = j ^ (n & 7);
            size_t src = (size_t)n * HID + khalf + jp * 8;
            async16(&Bh[g * 8], &Bth[src]);
            async16(&Bl[g * 8], &Btl[src]);
        }
    };

    stageB(0);
    #pragma unroll
    for (int i = 0; i < 8; i++) {
        int q = t + i * 256;
        int r = q >> 5, c4 = q & 31;
        int grow = row0 + r;
        float4 v = make_float4(0.f, 0.f, 0.f, 0.f);
        if (grow < N_NODES) v = *(const float4*)&comb[(size_t)grow * HID + c4 * 4];
        ushort4 uh, ul;
        split2(v.x, uh.x, ul.x); split2(v.y, uh.y, ul.y);
        split2(v.z, uh.z, ul.z); split2(v.w, uh.w, ul.w);
        int idx = (r * 128 + c4 * 4) ^ ((r & 7) << 3);
        *(ushort4*)&Ah[idx] = uh;
        *(ushort4*)&Al[idx] = ul;
    }
    __syncthreads();

    #pragma unroll
    for (int half = 0; half < 2; half++) {
        #pragma unroll
        for (int kk2 = 0; kk2 < 2; kk2++) {
            int kk = half * 2 + kk2;
            bf16x8 ah[2], al[2];
            #pragma unroll
            for (int mt = 0; mt < 2; mt++) {
                int arow = wr * 32 + mt * 16 + fr;
                int aidx = (arow * 128 + kk * 32 + fkg * 8) ^ ((arow & 7) << 3);
                ah[mt] = *(bf16x8*)&Ah[aidx];
                al[mt] = *(bf16x8*)&Al[aidx];
            }
            #pragma unroll
            for (int nt = 0; nt < 4; nt++) {
                int n = wc * 64 + nt * 16 + fr;
                int bidx = (n * 64 + kk2 * 32 + fkg * 8) ^ ((n & 7) << 3);
                bf16x8 bh = *(bf16x8*)&Bh[bidx];
                bf16x8 bl = *(bf16x8*)&Bl[bidx];
                #pragma unroll
                for (int mt = 0; mt < 2; mt++) {
                    acc[mt][nt] = MFMA16(al[mt], bh, acc[mt][nt]);
                    acc[mt][nt] = MFMA16(ah[mt], bl, acc[mt][nt]);
                    acc[mt][nt] = MFMA16(ah[mt], bh, acc[mt][nt]);
                }
            }
        }
        if (half == 0) {
            __syncthreads();
            stageB(64);
            __syncthreads();
        }
    }

    const int dcol = lane & 15;
    const int dr0 = (lane >> 4) * 4;
    #pragma unroll
    for (int nt = 0; nt < 4; nt++) {
        int gcol = wc * 64 + nt * 16 + dcol;
        float s = sb[gcol];
        #pragma unroll
        for (int mt = 0; mt < 2; mt++) {
            #pragma unroll
            for (int j = 0; j < 4; j++) {
                int grow = row0 + wr * 32 + mt * 16 + dr0 + j;
                if (grow < N_NODES) {
                    comb[(size_t)grow * HID + gcol] = fmaxf(acc[mt][nt][j], s);
                }
            }
        }
    }
}

// ---------------- output GEMM: out = h @ W_out + b_out (fp32 vector) ----------------
__launch_bounds__(256)
__global__ void gemm_out(const float* __restrict__ h, const float* __restrict__ Wo,
                         const float* __restrict__ bo, float* __restrict__ out) {
    __shared__ float As[64][129];
    __shared__ float Ws[128][40];
    const int t = threadIdx.x;
    const int row0 = blockIdx.x * 64;

    #pragma unroll
    for (int i = 0; i < 8; i++) {
        int q = t + i * 256;
        int r = q >> 5, c4 = q & 31;
        int grow = row0 + r;
        float4 v = make_float4(0.f, 0.f, 0.f, 0.f);
        if (grow < N_NODES) v = *(const float4*)&h[(size_t)grow * HID + c4 * 4];
        As[r][c4 * 4 + 0] = v.x;
        As[r][c4 * 4 + 1] = v.y;
        As[r][c4 * 4 + 2] = v.z;
        As[r][c4 * 4 + 3] = v.w;
    }
    #pragma unroll
    for (int i = 0; i < 20; i++) {
        int idx = t + i * 256;
        Ws[idx / 40][idx % 40] = Wo[idx];
    }
    __syncthreads();

    const int r = t >> 2;
    const int c0 = t & 3;
    float acc[10] = {};
    #pragma unroll 4
    for (int k = 0; k < HID; k++) {
        float a = As[r][k];
        #pragma unroll
        for (int i = 0; i < 10; i++) {
            acc[i] = fmaf(a, Ws[k][c0 + 4 * i], acc[i]);
        }
    }
    int grow = row0 + r;
    if (grow < N_NODES) {
        #pragma unroll
        for (int i = 0; i < 10; i++) {
            out[(size_t)grow * C_OUT + c0 + 4 * i] = acc[i] + bo[c0 + 4 * i];
        }
    }
}

// ---------------- launch ----------------
extern "C" void kernel_launch(void* const* d_in, const int* in_sizes, int n_in,
                              void* d_out, int out_size, void* d_ws, size_t ws_size,
                              hipStream_t stream) {
    const float* x   = (const float*)d_in[0];
    const int*   ei  = (const int*)d_in[1];
    const float* Wi  = (const float*)d_in[2];
    const float* bi  = (const float*)d_in[3];
    const float* Wls = (const float*)d_in[4];
    const float* sbs = (const float*)d_in[5];
    const float* Wo  = (const float*)d_in[6];
    const float* bo  = (const float*)d_in[7];
    float* out = (float*)d_out;

    float* dinv    = (float*)d_ws;                  // 50176 f
    int*   indeg   = (int*)(dinv + 50176);          // 50176 i
    int*   rowptr  = indeg + 50176;                 // 50304 i
    int*   cursor  = rowptr + 50304;                // 50176 i
    int*   bsum    = cursor + 50176;                // 256 i
    int*   boff    = bsum + 256;                    // 256 i
    int2*  csr     = (int2*)(boff + 256);           // 800000 int2 (6.4 MB)
    unsigned short* Wth  = (unsigned short*)(csr + 800000);
    unsigned short* Wtl  = Wth + 65536;
    unsigned short* Wlth = Wtl + 65536;
    unsigned short* Wltl = Wlth + 65536;
    float* x0 = (float*)(Wltl + 65536);             // 6.4M f (residual anchor, written once)
    float* hB = x0 + (size_t)N_NODES * HID;         // 6.4M f
    float* hC = hB + (size_t)N_NODES * HID;         // 6.4M f

    const int edgeBlocks = (E_EDGES + 255) / 256;
    const int gemmBlocks = (N_NODES + 63) / 64;
    const int aggBlocks  = (N_NODES + 7) / 8;

    hipMemsetAsync(indeg, 0, N_NODES * sizeof(int), stream);
    indeg_count<<<edgeBlocks, 256, 0, stream>>>(ei, indeg);
    scan_p1<<<SCAN_BLOCKS, 256, 0, stream>>>(indeg, bsum, dinv);
    scan_p2<<<1, 256, 0, stream>>>(bsum, boff, rowptr);
    scan_p3<<<SCAN_BLOCKS, 256, 0, stream>>>(indeg, boff, rowptr, cursor);
    csr_fill<<<edgeBlocks, 256, 0, stream>>>(ei, dinv, cursor, csr);
    wprep<<<(2 * F_IN * HID + 255) / 256, 256, 0, stream>>>(Wi, Wls, Wth, Wtl, Wlth, Wltl);

    gemm_in_mfma<<<gemmBlocks, 256, 0, stream>>>(x, Wth, Wtl, bi, x0);

    float* h = x0;
    for (int l = 0; l < N_LAYERS; l++) {
        float* next = (l & 1) ? hC : hB;
        aggregate<<<aggBlocks, 256, 0, stream>>>(rowptr, csr, dinv, h, x0, next);
        gemm_layer_mfma<<<gemmBlocks, 256, 0, stream>>>(Wlth + (size_t)l * HID * HID,
                                                        Wltl + (size_t)l * HID * HID,
                                                        sbs + (size_t)l * HID, next);
        h = next;
    }

    gemm_out<<<gemmBlocks, 256, 0, stream>>>(h, Wo, bo, out);
}